// Round 1
// baseline (1785.071 us; speedup 1.0000x reference)
//
#include <hip/hip_runtime.h>

typedef _Float16 half8 __attribute__((ext_vector_type(8)));
typedef float floatx16 __attribute__((ext_vector_type(16)));
typedef float float4v __attribute__((ext_vector_type(4)));

#define MTOT 131072   // B*T rows
#define DDIM 1024
#define TLEN 4096
#define BATCH 32
#define NMASK 2048

// --------- kernel 0: transpose + fp16-split W1 (scaled by 2^9, exact) ---------
// Wt[e][d] = hi/lo fp16 of W1[d][e] * 512
__global__ void k_wsplit(const float* __restrict__ W1, _Float16* __restrict__ Wthi,
                         _Float16* __restrict__ Wtlo)
{
  int flat = blockIdx.x * 256 + threadIdx.x;   // = e*1024 + d  (coalesced writes)
  int e = flat >> 10, d = flat & 1023;
  float w = W1[(size_t)d * DDIM + e] * 512.0f;
  _Float16 h = (_Float16)w;
  Wthi[flat] = h;
  Wtlo[flat] = (_Float16)(w - (float)h);
}

// --------- kernel 1: fused scores GEMM -----------------------------------------
// tile 128x256, 8 waves (2x4), wave-tile 64x64 = 2x2 frags of mfma_f32_32x32x16_f16
// A (x) staged fp32->hi/lo fp16 in LDS; B (Wt) read straight from L2.
// 3 MFMA products per frag pair: hi*hi + hi*lo + lo*hi  (split-fp16 ~ fp32 grade)
// epilogue: tanh(acc/512 + b1)*w2, reduce over cols -> partials[colblock][row]
__global__ __launch_bounds__(512, 2) void k_score(const float* __restrict__ x,
    const _Float16* __restrict__ Wthi, const _Float16* __restrict__ Wtlo,
    const float* __restrict__ b1, const float* __restrict__ w2,
    float* __restrict__ partials)
{
  __shared__ __align__(16) _Float16 Ahi[128 * 40];   // row stride 40 (80B): 2-way-free b128
  __shared__ __align__(16) _Float16 Alo[128 * 40];
  __shared__ float part_lds[4][128];

  const int tid  = threadIdx.x;
  const int lane = tid & 63;
  const int wave = tid >> 6;
  const int wr = wave >> 2, wn = wave & 3;
  const int l31 = lane & 31, l5 = lane >> 5;
  const int m0 = blockIdx.x * 128;
  const int n0 = blockIdx.y * 256;

  const int arow = tid >> 2, aseg = tid & 3;
  const float* xsrc = x + (size_t)(m0 + arow) * DDIM + aseg * 8;

  floatx16 acc[2][2] = {};

  for (int kk = 0; kk < DDIM; kk += 32) {
    // ---- B fragments from L2 (issued early to hide latency) ----
    half8 bh[2][2], bl[2][2];
#pragma unroll
    for (int nf = 0; nf < 2; nf++) {
      int col = n0 + wn * 64 + nf * 32 + l31;
      const _Float16* bp = Wthi + (size_t)col * DDIM + kk + l5 * 8;
      const _Float16* bq = Wtlo + (size_t)col * DDIM + kk + l5 * 8;
#pragma unroll
      for (int kc = 0; kc < 2; kc++) {
        bh[nf][kc] = *(const half8*)(bp + kc * 16);
        bl[nf][kc] = *(const half8*)(bq + kc * 16);
      }
    }
    // ---- load + split A ----
    float4v v0 = *(const float4v*)(xsrc + kk);
    float4v v1 = *(const float4v*)(xsrc + kk + 4);
    half8 hv, lv;
#pragma unroll
    for (int i = 0; i < 4; i++) {
      _Float16 h0 = (_Float16)v0[i]; hv[i] = h0;     lv[i] = (_Float16)(v0[i] - (float)h0);
      _Float16 h1 = (_Float16)v1[i]; hv[4 + i] = h1; lv[4 + i] = (_Float16)(v1[i] - (float)h1);
    }
    __syncthreads();                                  // prev iter's LDS reads done
    *(half8*)&Ahi[arow * 40 + aseg * 8] = hv;
    *(half8*)&Alo[arow * 40 + aseg * 8] = lv;
    __syncthreads();
    // ---- A fragments ----
    half8 ah[2][2], al[2][2];
#pragma unroll
    for (int mf = 0; mf < 2; mf++) {
      int row = wr * 64 + mf * 32 + l31;
#pragma unroll
      for (int kc = 0; kc < 2; kc++) {
        ah[mf][kc] = *(const half8*)&Ahi[row * 40 + kc * 16 + l5 * 8];
        al[mf][kc] = *(const half8*)&Alo[row * 40 + kc * 16 + l5 * 8];
      }
    }
    // ---- MFMA: 24 per wave per K-step ----
#pragma unroll
    for (int kc = 0; kc < 2; kc++)
#pragma unroll
      for (int mf = 0; mf < 2; mf++)
#pragma unroll
        for (int nf = 0; nf < 2; nf++) {
          acc[mf][nf] = __builtin_amdgcn_mfma_f32_32x32x16_f16(ah[mf][kc], bh[nf][kc], acc[mf][nf], 0, 0, 0);
          acc[mf][nf] = __builtin_amdgcn_mfma_f32_32x32x16_f16(ah[mf][kc], bl[nf][kc], acc[mf][nf], 0, 0, 0);
          acc[mf][nf] = __builtin_amdgcn_mfma_f32_32x32x16_f16(al[mf][kc], bh[nf][kc], acc[mf][nf], 0, 0, 0);
        }
  }

  // ---- epilogue: tanh + dot(w2) + row reduce ----
  float b1v[2], w2v[2];
#pragma unroll
  for (int nf = 0; nf < 2; nf++) {
    int col = n0 + wn * 64 + nf * 32 + l31;
    b1v[nf] = b1[col];
    w2v[nf] = w2[col];
  }
  const float inv512 = 1.0f / 512.0f;
#pragma unroll
  for (int mf = 0; mf < 2; mf++)
#pragma unroll
    for (int reg = 0; reg < 16; reg++) {
      float s = 0.0f;
#pragma unroll
      for (int nf = 0; nf < 2; nf++) {
        float pre = acc[mf][nf][reg] * inv512 + b1v[nf];
        float a = fabsf(pre);
        float e = __expf(-2.0f * a);
        float t = (1.0f - e) / (1.0f + e);            // tanh(|pre|)
        s += copysignf(t, pre) * w2v[nf];
      }
#pragma unroll
      for (int off = 1; off < 32; off <<= 1) s += __shfl_xor(s, off, 64);
      if (l31 == 0)
        part_lds[wn][wr * 64 + mf * 32 + (reg & 3) + 8 * (reg >> 2) + 4 * l5] = s;
    }
  __syncthreads();
  if (tid < 128) {
    float v = part_lds[0][tid] + part_lds[1][tid] + part_lds[2][tid] + part_lds[3][tid];
    partials[(size_t)blockIdx.y * MTOT + m0 + tid] = v;
  }
}

// --------- kernel 2: per-batch-row exact select (stable-argsort semantics) + softmax
__global__ void k_select(const float* __restrict__ partials, const float* __restrict__ b2,
                         float* __restrict__ weights)
{
  __shared__ float s_lds[TLEN];
  __shared__ unsigned long long keys[TLEN];
  __shared__ float red[20];
  const int b = blockIdx.x, tid = threadIdx.x;
  const float b2v = b2[0];

  for (int i = tid; i < TLEN; i += 1024) {
    size_t idx = (size_t)b * TLEN + i;
    float s = partials[idx] + partials[idx + (size_t)MTOT] +
              partials[idx + 2 * (size_t)MTOT] + partials[idx + 3 * (size_t)MTOT] + b2v;
    s_lds[i] = s;
    unsigned u = __float_as_uint(s);
    u = (u & 0x80000000u) ? ~u : (u | 0x80000000u);  // order-preserving float->uint
    keys[i] = ((unsigned long long)u << 32) | (unsigned)i;
  }
  __syncthreads();
  // bitonic sort ascending (key = (score, index) — matches stable argsort)
  for (int k = 2; k <= TLEN; k <<= 1)
    for (int j = k >> 1; j > 0; j >>= 1) {
      for (int i = tid; i < TLEN; i += 1024) {
        int p = i ^ j;
        if (p > i) {
          unsigned long long a = keys[i], c = keys[p];
          bool up = ((i & k) == 0);
          if ((a > c) == up) { keys[i] = c; keys[p] = a; }
        }
      }
      __syncthreads();
    }

  const unsigned long long thr = keys[NMASK];        // first KEPT pair
  unsigned um = (unsigned)(keys[TLEN - 1] >> 32);    // decode row max
  um = (um & 0x80000000u) ? (um ^ 0x80000000u) : ~um;
  const float m = __uint_as_float(um);

  float ev[4]; bool kp[4]; float zp = 0.0f;
#pragma unroll
  for (int q = 0; q < 4; q++) {
    int i = tid + q * 1024;
    float s = s_lds[i];
    unsigned u = __float_as_uint(s);
    u = (u & 0x80000000u) ? ~u : (u | 0x80000000u);
    unsigned long long key = ((unsigned long long)u << 32) | (unsigned)i;
    kp[q] = (key >= thr);
    ev[q] = __expf(s - m);
    if (kp[q]) zp += ev[q];
  }
#pragma unroll
  for (int off = 1; off < 64; off <<= 1) zp += __shfl_xor(zp, off, 64);
  if ((tid & 63) == 0) red[tid >> 6] = zp;
  __syncthreads();
  if (tid == 0) { float z = 0.0f; for (int i = 0; i < 16; i++) z += red[i]; red[16] = z; }
  __syncthreads();
  const float invZ = 1.0f / red[16];
#pragma unroll
  for (int q = 0; q < 4; q++) {
    int i = tid + q * 1024;
    weights[(size_t)b * TLEN + i] = kp[q] ? ev[q] * invZ : 0.0f;
  }
}

// --------- kernel 3: masked_output = x * weights[row] ---------
__global__ void k_scale(const float* __restrict__ x, const float* __restrict__ weights,
                        float* __restrict__ out)
{
  const size_t n4 = (size_t)MTOT * DDIM / 4;
  for (size_t f = (size_t)blockIdx.x * blockDim.x + threadIdx.x; f < n4;
       f += (size_t)gridDim.x * blockDim.x) {
    float w = weights[f >> 8];                       // 256 float4 per row
    float4v v = ((const float4v*)x)[f];
    ((float4v*)out)[f] = v * w;
  }
}

extern "C" void kernel_launch(void* const* d_in, const int* in_sizes, int n_in,
                              void* d_out, int out_size, void* d_ws, size_t ws_size,
                              hipStream_t stream)
{
  const float* x  = (const float*)d_in[0];
  const float* W1 = (const float*)d_in[1];
  const float* b1 = (const float*)d_in[2];
  const float* w2 = (const float*)d_in[3];
  const float* b2 = (const float*)d_in[4];
  float* out = (float*)d_out;
  float* weights = out + (size_t)MTOT * DDIM;        // output 1 region

  char* ws = (char*)d_ws;
  _Float16* Wthi  = (_Float16*)ws;                   // 2 MiB
  _Float16* Wtlo  = (_Float16*)(ws + (2u << 20));    // 2 MiB
  float*    parts = (float*)(ws + (4u << 20));       // 4*131072*4 = 2 MiB

  k_wsplit<<<4096, 256, 0, stream>>>(W1, Wthi, Wtlo);
  k_score<<<dim3(1024, 4), 512, 0, stream>>>(x, Wthi, Wtlo, b1, w2, parts);
  k_select<<<BATCH, 1024, 0, stream>>>(parts, b2, weights);
  k_scale<<<2048, 256, 0, stream>>>(x, weights, out);
}

// Round 2
// 1697.524 us; speedup vs baseline: 1.0516x; 1.0516x over previous
//
#include <hip/hip_runtime.h>

typedef _Float16 half8 __attribute__((ext_vector_type(8)));
typedef float floatx16 __attribute__((ext_vector_type(16)));
typedef float float4v __attribute__((ext_vector_type(4)));

#define MTOT 131072   // B*T rows
#define DDIM 1024
#define TLEN 4096
#define BATCH 32
#define NMASK 2048

// --------- kernel 0: transpose + fp16-split W1 (scaled by 2^9, exact) ---------
__global__ void k_wsplit(const float* __restrict__ W1, _Float16* __restrict__ Wthi,
                         _Float16* __restrict__ Wtlo)
{
  int flat = blockIdx.x * 256 + threadIdx.x;   // = e*1024 + d  (coalesced writes)
  int e = flat >> 10, d = flat & 1023;
  float w = W1[(size_t)d * DDIM + e] * 512.0f;
  _Float16 h = (_Float16)w;
  Wthi[flat] = h;
  Wtlo[flat] = (_Float16)(w - (float)h);
}

// --------- kernel 1: fused scores GEMM, software-pipelined --------------------
// tile 128x256, 8 waves (2x4), wave-tile 64x64 = 2x2 frags of mfma_f32_32x32x16_f16
// pipeline: x prefetch distance 2 (reg), B prefetch distance 1 (reg dbuf),
// LDS A double-buffered -> ONE barrier per K-step.
__global__ __launch_bounds__(512, 2) void k_score(const float* __restrict__ x,
    const _Float16* __restrict__ Wthi, const _Float16* __restrict__ Wtlo,
    const float* __restrict__ b1, const float* __restrict__ w2,
    float* __restrict__ partials)
{
  __shared__ __align__(16) _Float16 Ahi[2][128 * 40];   // stride 40: b128 4-way max
  __shared__ __align__(16) _Float16 Alo[2][128 * 40];
  __shared__ float part_lds[4][128];

  const int tid  = threadIdx.x;
  const int lane = tid & 63;
  const int wave = tid >> 6;
  const int wr = wave >> 2, wn = wave & 3;
  const int l31 = lane & 31, l5 = lane >> 5;
  const int m0 = blockIdx.x * 128;
  const int n0 = blockIdx.y * 256;

  const int arow = tid >> 2, aseg = tid & 3;
  const float* xsrc = x + (size_t)(m0 + arow) * DDIM + aseg * 8;

  const _Float16* bsrc_hi[2];
  const _Float16* bsrc_lo[2];
#pragma unroll
  for (int nf = 0; nf < 2; nf++) {
    int col = n0 + wn * 64 + nf * 32 + l31;
    bsrc_hi[nf] = Wthi + (size_t)col * DDIM + l5 * 8;
    bsrc_lo[nf] = Wtlo + (size_t)col * DDIM + l5 * 8;
  }

  floatx16 acc[2][2] = {};
  half8 bh0[2][2], bl0[2][2], bh1[2][2], bl1[2][2];
  float4v vA0, vA1, vB0, vB1;

  // ---- prologue: x(0) -> buf0; vA = x(32); B(0) -> set0 ----
  {
    float4v v0 = *(const float4v*)(xsrc);
    float4v v1 = *(const float4v*)(xsrc + 4);
    half8 hv, lv;
#pragma unroll
    for (int i = 0; i < 4; i++) {
      _Float16 h0 = (_Float16)v0[i]; hv[i] = h0;     lv[i] = (_Float16)(v0[i] - (float)h0);
      _Float16 h1 = (_Float16)v1[i]; hv[4 + i] = h1; lv[4 + i] = (_Float16)(v1[i] - (float)h1);
    }
    *(half8*)&Ahi[0][arow * 40 + aseg * 8] = hv;
    *(half8*)&Alo[0][arow * 40 + aseg * 8] = lv;
    vA0 = *(const float4v*)(xsrc + 32);
    vA1 = *(const float4v*)(xsrc + 36);
#pragma unroll
    for (int nf = 0; nf < 2; nf++)
#pragma unroll
      for (int kc = 0; kc < 2; kc++) {
        bh0[nf][kc] = *(const half8*)(bsrc_hi[nf] + kc * 16);
        bl0[nf][kc] = *(const half8*)(bsrc_lo[nf] + kc * 16);
      }
  }

  // one K-step: BUF = LDS buffer holding this step's A; BH/BL = this step's B;
  // BHN/BLN receive B(kk+32); VC0/VC1 hold x(kk+32) (split+stored to BUF^1);
  // VN0/VN1 receive x(kk+64).
#define KSTEP(BUF, BH, BL, BHN, BLN, VC0, VC1, VN0, VN1, kk)                          \
  {                                                                                   \
    const int kn1 = ((kk) + 32) & (DDIM - 1);                                         \
    const int kn2 = ((kk) + 64) & (DDIM - 1);                                         \
    VN0 = *(const float4v*)(xsrc + kn2);                                              \
    VN1 = *(const float4v*)(xsrc + kn2 + 4);                                          \
    _Pragma("unroll")                                                                 \
    for (int nf = 0; nf < 2; nf++)                                                    \
      _Pragma("unroll")                                                               \
      for (int kc = 0; kc < 2; kc++) {                                                \
        BHN[nf][kc] = *(const half8*)(bsrc_hi[nf] + kn1 + kc * 16);                   \
        BLN[nf][kc] = *(const half8*)(bsrc_lo[nf] + kn1 + kc * 16);                   \
      }                                                                               \
    __syncthreads();                                                                  \
    half8 ah[2][2], al[2][2];                                                         \
    _Pragma("unroll")                                                                 \
    for (int mf = 0; mf < 2; mf++) {                                                  \
      int row = wr * 64 + mf * 32 + l31;                                              \
      _Pragma("unroll")                                                               \
      for (int kc = 0; kc < 2; kc++) {                                                \
        ah[mf][kc] = *(const half8*)&Ahi[BUF][row * 40 + kc * 16 + l5 * 8];           \
        al[mf][kc] = *(const half8*)&Alo[BUF][row * 40 + kc * 16 + l5 * 8];           \
      }                                                                               \
    }                                                                                 \
    _Pragma("unroll")                                                                 \
    for (int kc = 0; kc < 2; kc++)                                                    \
      _Pragma("unroll")                                                               \
      for (int mf = 0; mf < 2; mf++)                                                  \
        _Pragma("unroll")                                                             \
        for (int nf = 0; nf < 2; nf++) {                                              \
          acc[mf][nf] = __builtin_amdgcn_mfma_f32_32x32x16_f16(ah[mf][kc], BH[nf][kc], acc[mf][nf], 0, 0, 0); \
          acc[mf][nf] = __builtin_amdgcn_mfma_f32_32x32x16_f16(ah[mf][kc], BL[nf][kc], acc[mf][nf], 0, 0, 0); \
          acc[mf][nf] = __builtin_amdgcn_mfma_f32_32x32x16_f16(al[mf][kc], BH[nf][kc], acc[mf][nf], 0, 0, 0); \
        }                                                                             \
    half8 hv, lv;                                                                     \
    _Pragma("unroll")                                                                 \
    for (int i = 0; i < 4; i++) {                                                     \
      _Float16 h0 = (_Float16)VC0[i]; hv[i] = h0;     lv[i] = (_Float16)(VC0[i] - (float)h0); \
      _Float16 h1 = (_Float16)VC1[i]; hv[4 + i] = h1; lv[4 + i] = (_Float16)(VC1[i] - (float)h1); \
    }                                                                                 \
    *(half8*)&Ahi[BUF ^ 1][arow * 40 + aseg * 8] = hv;                                \
    *(half8*)&Alo[BUF ^ 1][arow * 40 + aseg * 8] = lv;                                \
  }

  for (int kk = 0; kk < DDIM; kk += 64) {
    KSTEP(0, bh0, bl0, bh1, bl1, vA0, vA1, vB0, vB1, kk)
    KSTEP(1, bh1, bl1, bh0, bl0, vB0, vB1, vA0, vA1, kk + 32)
  }
#undef KSTEP

  // ---- epilogue: tanh + dot(w2) + row reduce ----
  float b1v[2], w2v[2];
#pragma unroll
  for (int nf = 0; nf < 2; nf++) {
    int col = n0 + wn * 64 + nf * 32 + l31;
    b1v[nf] = b1[col];
    w2v[nf] = w2[col];
  }
  const float inv512 = 1.0f / 512.0f;
#pragma unroll
  for (int mf = 0; mf < 2; mf++)
#pragma unroll
    for (int reg = 0; reg < 16; reg++) {
      float s = 0.0f;
#pragma unroll
      for (int nf = 0; nf < 2; nf++) {
        float pre = acc[mf][nf][reg] * inv512 + b1v[nf];
        float a = fabsf(pre);
        float e = __expf(-2.0f * a);
        float t = (1.0f - e) / (1.0f + e);            // tanh(|pre|)
        s += copysignf(t, pre) * w2v[nf];
      }
#pragma unroll
      for (int off = 1; off < 32; off <<= 1) s += __shfl_xor(s, off, 64);
      if (l31 == 0)
        part_lds[wn][wr * 64 + mf * 32 + (reg & 3) + 8 * (reg >> 2) + 4 * l5] = s;
    }
  __syncthreads();
  if (tid < 128) {
    float v = part_lds[0][tid] + part_lds[1][tid] + part_lds[2][tid] + part_lds[3][tid];
    partials[(size_t)blockIdx.y * MTOT + m0 + tid] = v;
  }
}

// --------- kernel 2: per-batch-row exact select (stable-argsort semantics) + softmax
__global__ void k_select(const float* __restrict__ partials, const float* __restrict__ b2,
                         float* __restrict__ weights)
{
  __shared__ float s_lds[TLEN];
  __shared__ unsigned long long keys[TLEN];
  __shared__ float red[20];
  const int b = blockIdx.x, tid = threadIdx.x;
  const float b2v = b2[0];

  for (int i = tid; i < TLEN; i += 1024) {
    size_t idx = (size_t)b * TLEN + i;
    float s = partials[idx] + partials[idx + (size_t)MTOT] +
              partials[idx + 2 * (size_t)MTOT] + partials[idx + 3 * (size_t)MTOT] + b2v;
    s_lds[i] = s;
    unsigned u = __float_as_uint(s);
    u = (u & 0x80000000u) ? ~u : (u | 0x80000000u);  // order-preserving float->uint
    keys[i] = ((unsigned long long)u << 32) | (unsigned)i;
  }
  __syncthreads();
  // bitonic sort ascending (key = (score, index) — matches stable argsort)
  for (int k = 2; k <= TLEN; k <<= 1)
    for (int j = k >> 1; j > 0; j >>= 1) {
      for (int i = tid; i < TLEN; i += 1024) {
        int p = i ^ j;
        if (p > i) {
          unsigned long long a = keys[i], c = keys[p];
          bool up = ((i & k) == 0);
          if ((a > c) == up) { keys[i] = c; keys[p] = a; }
        }
      }
      __syncthreads();
    }

  const unsigned long long thr = keys[NMASK];        // first KEPT pair
  unsigned um = (unsigned)(keys[TLEN - 1] >> 32);    // decode row max
  um = (um & 0x80000000u) ? (um ^ 0x80000000u) : ~um;
  const float m = __uint_as_float(um);

  float ev[4]; bool kp[4]; float zp = 0.0f;
#pragma unroll
  for (int q = 0; q < 4; q++) {
    int i = tid + q * 1024;
    float s = s_lds[i];
    unsigned u = __float_as_uint(s);
    u = (u & 0x80000000u) ? ~u : (u | 0x80000000u);
    unsigned long long key = ((unsigned long long)u << 32) | (unsigned)i;
    kp[q] = (key >= thr);
    ev[q] = __expf(s - m);
    if (kp[q]) zp += ev[q];
  }
#pragma unroll
  for (int off = 1; off < 64; off <<= 1) zp += __shfl_xor(zp, off, 64);
  if ((tid & 63) == 0) red[tid >> 6] = zp;
  __syncthreads();
  if (tid == 0) { float z = 0.0f; for (int i = 0; i < 16; i++) z += red[i]; red[16] = z; }
  __syncthreads();
  const float invZ = 1.0f / red[16];
#pragma unroll
  for (int q = 0; q < 4; q++) {
    int i = tid + q * 1024;
    weights[(size_t)b * TLEN + i] = kp[q] ? ev[q] * invZ : 0.0f;
  }
}

// --------- kernel 3: masked_output = x * weights[row] ---------
__global__ void k_scale(const float* __restrict__ x, const float* __restrict__ weights,
                        float* __restrict__ out)
{
  const size_t n4 = (size_t)MTOT * DDIM / 4;
  for (size_t f = (size_t)blockIdx.x * blockDim.x + threadIdx.x; f < n4;
       f += (size_t)gridDim.x * blockDim.x) {
    float w = weights[f >> 8];                       // 256 float4 per row
    float4v v = ((const float4v*)x)[f];
    ((float4v*)out)[f] = v * w;
  }
}

extern "C" void kernel_launch(void* const* d_in, const int* in_sizes, int n_in,
                              void* d_out, int out_size, void* d_ws, size_t ws_size,
                              hipStream_t stream)
{
  const float* x  = (const float*)d_in[0];
  const float* W1 = (const float*)d_in[1];
  const float* b1 = (const float*)d_in[2];
  const float* w2 = (const float*)d_in[3];
  const float* b2 = (const float*)d_in[4];
  float* out = (float*)d_out;
  float* weights = out + (size_t)MTOT * DDIM;        // output 1 region

  char* ws = (char*)d_ws;
  _Float16* Wthi  = (_Float16*)ws;                   // 2 MiB
  _Float16* Wtlo  = (_Float16*)(ws + (2u << 20));    // 2 MiB
  float*    parts = (float*)(ws + (4u << 20));       // 4*131072*4 = 2 MiB

  k_wsplit<<<4096, 256, 0, stream>>>(W1, Wthi, Wtlo);
  k_score<<<dim3(1024, 4), 512, 0, stream>>>(x, Wthi, Wtlo, b1, w2, parts);
  k_select<<<BATCH, 1024, 0, stream>>>(parts, b2, weights);
  k_scale<<<2048, 256, 0, stream>>>(x, weights, out);
}

// Round 3
// 1560.300 us; speedup vs baseline: 1.1441x; 1.0879x over previous
//
#include <hip/hip_runtime.h>

typedef _Float16 half8 __attribute__((ext_vector_type(8)));
typedef _Float16 half4v __attribute__((ext_vector_type(4)));
typedef float floatx16 __attribute__((ext_vector_type(16)));
typedef float float4v __attribute__((ext_vector_type(4)));

#define MTOT 131072   // B*T rows
#define DDIM 1024
#define TLEN 4096
#define BATCH 32
#define NMASK 2048
#define ASTRIDE 136   // f16 elems; 272B row stride -> bank-clean b128 reads

// --------- kernel 0: transpose + fp16-split W1 (scaled by 2^9, exact) ---------
__global__ void k_wsplit(const float* __restrict__ W1, _Float16* __restrict__ Wthi,
                         _Float16* __restrict__ Wtlo)
{
  int flat = blockIdx.x * 256 + threadIdx.x;   // = e*1024 + d  (coalesced writes)
  int e = flat >> 10, d = flat & 1023;
  float w = W1[(size_t)d * DDIM + e] * 512.0f;
  _Float16 h = (_Float16)w;
  Wthi[flat] = h;
  Wtlo[flat] = (_Float16)(w - (float)h);
}

// --------- kernel 1: fused scores GEMM, BK=128 megastep ------------------------
// tile 128 rows x 256 cols, 8 waves (2x4), wave 64x64 = 2x2 frags of 32x32x16.
// Barrier interval = 128 K (768 cyc MFMA/wave) so the compiler's vmcnt(0)-at-
// barrier drain is amortized; x prefetch for t+1 issued right AFTER barrier2 so
// it is ~768 cyc old when the next barrier drains it.
__global__ __launch_bounds__(512, 4) void k_score(const float* __restrict__ x,
    const _Float16* __restrict__ Wthi, const _Float16* __restrict__ Wtlo,
    const float* __restrict__ b1, const float* __restrict__ w2,
    float* __restrict__ partials)
{
  __shared__ __align__(16) _Float16 Ahi[128 * ASTRIDE];   // 34 KB
  __shared__ __align__(16) _Float16 Alo[128 * ASTRIDE];   // 34 KB
  __shared__ float part_lds[4][128];

  const int tid  = threadIdx.x;
  const int lane = tid & 63;
  const int wave = tid >> 6;
  const int wr = wave >> 2, wn = wave & 3;
  const int l31 = lane & 31, l5 = lane >> 5;
  const int n0 = blockIdx.x * 256;   // 4 col-tiles: dispatch-adjacent blocks share the
  const int m0 = blockIdx.y * 128;   // same x row-panel -> HBM fetch ~once

  // x staging: round j covers rows [j*16, j*16+16); thread -> (row j*16 + tid>>5,
  // float4 at col (tid&31)*4). 32 lanes x 16B contiguous per row = fully coalesced.
  const int xrow = tid >> 5;         // 0..15
  const int xk   = (tid & 31) * 4;   // 0..124
  const float* xbase = x + (size_t)(m0 + xrow) * DDIM + xk;

  const _Float16* bsrc_hi[2];
  const _Float16* bsrc_lo[2];
#pragma unroll
  for (int nf = 0; nf < 2; nf++) {
    int col = n0 + wn * 64 + nf * 32 + l31;
    bsrc_hi[nf] = Wthi + (size_t)col * DDIM + l5 * 8;
    bsrc_lo[nf] = Wtlo + (size_t)col * DDIM + l5 * 8;
  }

  floatx16 acc[2][2] = {};
  float4v xv[8];

  // prologue: x(t=0)
#pragma unroll
  for (int j = 0; j < 8; j++)
    xv[j] = *(const float4v*)(xbase + (size_t)j * 16 * DDIM);

  for (int t = 0; t < 8; ++t) {
    __syncthreads();                 // LDS free (prev megastep's reads done)
#pragma unroll
    for (int j = 0; j < 8; j++) {    // split fp32 -> hi/lo f16, write LDS
      half4v hv, lv;
#pragma unroll
      for (int i = 0; i < 4; i++) {
        float w = xv[j][i];
        _Float16 h = (_Float16)w;
        hv[i] = h; lv[i] = (_Float16)(w - (float)h);
      }
      int r = j * 16 + xrow;
      *(half4v*)&Ahi[r * ASTRIDE + xk] = hv;
      *(half4v*)&Alo[r * ASTRIDE + xk] = lv;
    }
    __syncthreads();                 // LDS ready

    const int kk = t * 128;
    const int tn = ((t + 1) & 7) * 128;
    // prefetch next megastep's x NOW: drained (free) at next barrier, ~768 cyc away
#pragma unroll
    for (int j = 0; j < 8; j++)
      xv[j] = *(const float4v*)(xbase + (size_t)j * 16 * DDIM + tn);

#pragma unroll
    for (int kc = 0; kc < 8; ++kc) {
      half8 bh[2], bl[2], ah[2], al[2];
#pragma unroll
      for (int nf = 0; nf < 2; nf++) {
        bh[nf] = *(const half8*)(bsrc_hi[nf] + kk + kc * 16);
        bl[nf] = *(const half8*)(bsrc_lo[nf] + kk + kc * 16);
      }
#pragma unroll
      for (int mf = 0; mf < 2; mf++) {
        int row = wr * 64 + mf * 32 + l31;
        ah[mf] = *(const half8*)&Ahi[row * ASTRIDE + kc * 16 + l5 * 8];
        al[mf] = *(const half8*)&Alo[row * ASTRIDE + kc * 16 + l5 * 8];
      }
#pragma unroll
      for (int mf = 0; mf < 2; mf++)
#pragma unroll
        for (int nf = 0; nf < 2; nf++) {
          acc[mf][nf] = __builtin_amdgcn_mfma_f32_32x32x16_f16(ah[mf], bh[nf], acc[mf][nf], 0, 0, 0);
          acc[mf][nf] = __builtin_amdgcn_mfma_f32_32x32x16_f16(ah[mf], bl[nf], acc[mf][nf], 0, 0, 0);
          acc[mf][nf] = __builtin_amdgcn_mfma_f32_32x32x16_f16(al[mf], bh[nf], acc[mf][nf], 0, 0, 0);
        }
    }
  }

  // ---- epilogue: tanh + dot(w2) + row reduce ----
  float b1v[2], w2v[2];
#pragma unroll
  for (int nf = 0; nf < 2; nf++) {
    int col = n0 + wn * 64 + nf * 32 + l31;
    b1v[nf] = b1[col];
    w2v[nf] = w2[col];
  }
  const float inv512 = 1.0f / 512.0f;
#pragma unroll
  for (int mf = 0; mf < 2; mf++)
#pragma unroll
    for (int reg = 0; reg < 16; reg++) {
      float s = 0.0f;
#pragma unroll
      for (int nf = 0; nf < 2; nf++) {
        float pre = acc[mf][nf][reg] * inv512 + b1v[nf];
        float a = fabsf(pre);
        float e = __expf(-2.0f * a);
        float t = (1.0f - e) / (1.0f + e);            // tanh(|pre|)
        s += copysignf(t, pre) * w2v[nf];
      }
#pragma unroll
      for (int off = 1; off < 32; off <<= 1) s += __shfl_xor(s, off, 64);
      if (l31 == 0)
        part_lds[wn][wr * 64 + mf * 32 + (reg & 3) + 8 * (reg >> 2) + 4 * l5] = s;
    }
  __syncthreads();
  if (tid < 128) {
    float v = part_lds[0][tid] + part_lds[1][tid] + part_lds[2][tid] + part_lds[3][tid];
    partials[(size_t)blockIdx.x * MTOT + m0 + tid] = v;
  }
}

// --------- kernel 2: per-batch-row exact select (stable-argsort semantics) + softmax
__global__ void k_select(const float* __restrict__ partials, const float* __restrict__ b2,
                         float* __restrict__ weights)
{
  __shared__ float s_lds[TLEN];
  __shared__ unsigned long long keys[TLEN];
  __shared__ float red[20];
  const int b = blockIdx.x, tid = threadIdx.x;
  const float b2v = b2[0];

  for (int i = tid; i < TLEN; i += 1024) {
    size_t idx = (size_t)b * TLEN + i;
    float s = partials[idx] + partials[idx + (size_t)MTOT] +
              partials[idx + 2 * (size_t)MTOT] + partials[idx + 3 * (size_t)MTOT] + b2v;
    s_lds[i] = s;
    unsigned u = __float_as_uint(s);
    u = (u & 0x80000000u) ? ~u : (u | 0x80000000u);  // order-preserving float->uint
    keys[i] = ((unsigned long long)u << 32) | (unsigned)i;
  }
  __syncthreads();
  // bitonic sort ascending (key = (score, index) — matches stable argsort)
  for (int k = 2; k <= TLEN; k <<= 1)
    for (int j = k >> 1; j > 0; j >>= 1) {
      for (int i = tid; i < TLEN; i += 1024) {
        int p = i ^ j;
        if (p > i) {
          unsigned long long a = keys[i], c = keys[p];
          bool up = ((i & k) == 0);
          if ((a > c) == up) { keys[i] = c; keys[p] = a; }
        }
      }
      __syncthreads();
    }

  const unsigned long long thr = keys[NMASK];        // first KEPT pair
  unsigned um = (unsigned)(keys[TLEN - 1] >> 32);    // decode row max
  um = (um & 0x80000000u) ? (um ^ 0x80000000u) : ~um;
  const float m = __uint_as_float(um);

  float ev[4]; bool kp[4]; float zp = 0.0f;
#pragma unroll
  for (int q = 0; q < 4; q++) {
    int i = tid + q * 1024;
    float s = s_lds[i];
    unsigned u = __float_as_uint(s);
    u = (u & 0x80000000u) ? ~u : (u | 0x80000000u);
    unsigned long long key = ((unsigned long long)u << 32) | (unsigned)i;
    kp[q] = (key >= thr);
    ev[q] = __expf(s - m);
    if (kp[q]) zp += ev[q];
  }
#pragma unroll
  for (int off = 1; off < 64; off <<= 1) zp += __shfl_xor(zp, off, 64);
  if ((tid & 63) == 0) red[tid >> 6] = zp;
  __syncthreads();
  if (tid == 0) { float z = 0.0f; for (int i = 0; i < 16; i++) z += red[i]; red[16] = z; }
  __syncthreads();
  const float invZ = 1.0f / red[16];
#pragma unroll
  for (int q = 0; q < 4; q++) {
    int i = tid + q * 1024;
    weights[(size_t)b * TLEN + i] = kp[q] ? ev[q] * invZ : 0.0f;
  }
}

// --------- kernel 3: masked_output = x * weights[row] ---------
__global__ void k_scale(const float* __restrict__ x, const float* __restrict__ weights,
                        float* __restrict__ out)
{
  const size_t n4 = (size_t)MTOT * DDIM / 4;
  for (size_t f = (size_t)blockIdx.x * blockDim.x + threadIdx.x; f < n4;
       f += (size_t)gridDim.x * blockDim.x) {
    float w = weights[f >> 8];                       // 256 float4 per row
    float4v v = ((const float4v*)x)[f];
    ((float4v*)out)[f] = v * w;
  }
}

extern "C" void kernel_launch(void* const* d_in, const int* in_sizes, int n_in,
                              void* d_out, int out_size, void* d_ws, size_t ws_size,
                              hipStream_t stream)
{
  const float* x  = (const float*)d_in[0];
  const float* W1 = (const float*)d_in[1];
  const float* b1 = (const float*)d_in[2];
  const float* w2 = (const float*)d_in[3];
  const float* b2 = (const float*)d_in[4];
  float* out = (float*)d_out;
  float* weights = out + (size_t)MTOT * DDIM;        // output 1 region

  char* ws = (char*)d_ws;
  _Float16* Wthi  = (_Float16*)ws;                   // 2 MiB
  _Float16* Wtlo  = (_Float16*)(ws + (2u << 20));    // 2 MiB
  float*    parts = (float*)(ws + (4u << 20));       // 4*131072*4 = 2 MiB

  k_wsplit<<<4096, 256, 0, stream>>>(W1, Wthi, Wtlo);
  k_score<<<dim3(4, 1024), 512, 0, stream>>>(x, Wthi, Wtlo, b1, w2, parts);
  k_select<<<BATCH, 1024, 0, stream>>>(parts, b2, weights);
  k_scale<<<2048, 256, 0, stream>>>(x, weights, out);
}